// Round 4
// baseline (974.427 us; speedup 1.0000x reference)
//
#include <hip/hip_runtime.h>
#include <math.h>

// ---------------------------------------------------------------------------
// RecurrentNatureCNN: conv1(8x8,s4) -> conv2(4x4,s2) -> conv3(3x3,s1) -> FC
//                     -> LSTM(T=64,B=32,H=256)
// N = T*B = 2048 images.
// R12: = R11 with the register cap actually granted. R11's
//      __launch_bounds__(512,2) was interpreted as 2 blocks/CU -> 4 waves/
//      SIMD -> 128-VGPR cap -> 192 weight dwords spilled to scratch INSIDE
//      the step loop (WRITE_SIZE 2->8.6 MB, 491 us). R12 pins occupancy via
//      amdgpu_waves_per_eu(2,2) (2 waves/SIMD = the minimum a 512-thread
//      block needs anyway) -> 256-VGPR budget; ~215 live regs fit.
//      LSTM partition (unchanged from R11): thread (u,half) holds full row
//      half*256+u (i/f) + half of g-row 512+u = 192 dw in regs; o-gate in
//      LDS (128 KB), opposite k-half per thread; 3 KB LDS exchange combines.
//      conv/GEMM stages unchanged from R8.
// ---------------------------------------------------------------------------

#define NIMG 2048

typedef _Float16 half2_t __attribute__((ext_vector_type(2)));
typedef __fp16 fp16x2_t __attribute__((ext_vector_type(2)));

__device__ inline unsigned short f2h_bits(float f) {
    union { _Float16 h; unsigned short u; } x;
    x.h = (_Float16)f;
    return x.u;
}

__device__ inline unsigned pack2_rne(float a, float b) {
    return (unsigned)f2h_bits(a) | ((unsigned)f2h_bits(b) << 16);
}

__device__ inline unsigned pack2_fast(float a, float b) {
#if __has_builtin(__builtin_amdgcn_cvt_pkrtz)
    union { fp16x2_t h; unsigned u; } x;
    x.h = __builtin_amdgcn_cvt_pkrtz(a, b);
    return x.u;
#else
    return pack2_rne(a, b);
#endif
}

__device__ inline float dot2(unsigned hu, unsigned wu, float acc) {
    union { unsigned u; half2_t h; } a, b;
    a.u = hu; b.u = wu;
#if __has_builtin(__builtin_amdgcn_fdot2)
    return __builtin_amdgcn_fdot2(a.h, b.h, acc, false);
#else
    return acc + (float)a.h.x * (float)b.h.x + (float)a.h.y * (float)b.h.y;
#endif
}

__device__ inline float fast_tanh(float x) {
    return 1.0f - 2.0f / (__expf(2.0f * x) + 1.0f);
}

// ---- generic small transpose: in (R,C) -> out (C,R) -----------------------
__global__ void transpose_kernel(const float* __restrict__ in, float* __restrict__ out,
                                 int R, int C) {
    int idx = blockIdx.x * 256 + threadIdx.x;
    if (idx < R * C) {
        int r = idx / C, c = idx - r * C;
        out[c * R + r] = in[idx];
    }
}

// ---- pack whh (1024,256) fp32 -> f16x2 pairs, uint4-interleaved by row -----
// wp dword index = d4*4096 + row*4 + j   (d4 = k/8, j selects k-pair within 8)
// i.e. as uint4: wp4[d4*1024 + row] = row's packed k = [d4*8, d4*8+8).
__global__ void pack_whh_pairs_kernel(const float* __restrict__ whh,
                                      unsigned* __restrict__ wp) {
    int idx = blockIdx.x * 256 + threadIdx.x;  // 0..131071
    if (idx >= 131072) return;
    int d4 = idx >> 12;
    int rem = idx & 4095;
    int row = rem >> 2;
    int j = idx & 3;
    int k0 = d4 * 8 + j * 2;
    const float* src = whh + (size_t)row * 256 + k0;
    wp[idx] = pack2_rne(src[0], src[1]);
}

// ---- pack w1 (32,4,8,8) fp32 -> f16x2 pairs along kx: w1p[oc][ic][ky][kxp] -
__global__ void pack_w1_kernel(const float* __restrict__ w1, unsigned* __restrict__ w1p) {
    int idx = blockIdx.x * 256 + threadIdx.x;  // 0..4095
    if (idx >= 4096) return;
    int oc = idx >> 7, rem = idx & 127;
    int ic = rem >> 5, ky = (rem >> 2) & 7, kxp = rem & 3;
    const float* src = w1 + (((size_t)oc * 4 + ic) * 8 + ky) * 8 + kxp * 2;
    w1p[idx] = pack2_rne(src[0], src[1]);
}

// ---- pack w2 (64,32,4,4) fp32 -> f16x2 pairs: w2p[(ic*4+ky)*2+kxp][oc] -----
__global__ void pack_w2_kernel(const float* __restrict__ w2, unsigned* __restrict__ w2p) {
    int idx = blockIdx.x * 256 + threadIdx.x;  // 0..16383
    if (idx >= 16384) return;
    int p = idx >> 6, oc = idx & 63;
    int ic = p >> 3, ky = (p >> 1) & 3, kxp = p & 1;
    const float* src = w2 + (size_t)oc * 512 + ic * 16 + ky * 4 + kxp * 2;
    w2p[idx] = pack2_rne(src[0], src[1]);
}

// ---- conv1: x (n,4,64,64)/255 -> relu -> z1 f16 (n,32,15,16 padded) --------
__global__ __launch_bounds__(1024) void conv1_kernel(const float* __restrict__ x,
                                                     const unsigned* __restrict__ w1p,
                                                     const float* __restrict__ b,
                                                     unsigned short* __restrict__ z1) {
    __shared__ unsigned short xs[4 * 64 * 64];  // f16, 32768 B
    int n = blockIdx.x;
    int tid = threadIdx.x;
    const float* xp = x + (size_t)n * 16384;
    const float inv = 1.0f / 255.0f;
    for (int i = tid * 4; i < 16384; i += 4096) {
        float4 v = *(const float4*)(xp + i);
        uint2 q;
        q.x = pack2_fast(v.x * inv, v.y * inv);
        q.y = pack2_fast(v.z * inv, v.w * inv);
        *(uint2*)&xs[i] = q;
    }
    __syncthreads();
    int lane = tid & 63, wave = tid >> 6;
    int gg = __builtin_amdgcn_readfirstlane(wave & 3);
    int pos = (wave >> 2) * 64 + lane;  // 0..255
    if (pos < 225) {
        int oy = pos / 15, ox = pos - oy * 15;
        float acc[8];
        const float* bp = b + gg * 8;
#pragma unroll
        for (int u = 0; u < 8; ++u) acc[u] = bp[u];
        for (int ic = 0; ic < 4; ++ic) {
#pragma unroll
            for (int ky = 0; ky < 8; ++ky) {
                const unsigned short* row = &xs[(ic * 64 + oy * 4 + ky) * 64 + ox * 4];
                uint2 qa = *(const uint2*)row;        // cols +0..3 (2 pairs)
                uint2 qb = *(const uint2*)(row + 4);  // cols +4..7 (2 pairs)
                const unsigned* wp = w1p + ((((gg * 8) * 4 + ic) * 8 + ky) * 4);
#pragma unroll
                for (int u = 0; u < 8; ++u) {
                    const unsigned* wu = wp + u * 128;  // (oc stride 4*8*4)
                    acc[u] = dot2(qa.x, wu[0], acc[u]);
                    acc[u] = dot2(qa.y, wu[1], acc[u]);
                    acc[u] = dot2(qb.x, wu[2], acc[u]);
                    acc[u] = dot2(qb.y, wu[3], acc[u]);
                }
            }
        }
        unsigned short* op = z1 + (size_t)n * 7680 + (gg * 8) * 240 + oy * 16 + ox;
#pragma unroll
        for (int u = 0; u < 8; ++u) op[u * 240] = f2h_bits(fmaxf(acc[u], 0.0f));
    }
}

// ---- conv2: z1 f16 (n,32,15,16) -> relu -> z2 fp32 (n,64,6,6) --------------
__global__ __launch_bounds__(768) void conv2_kernel(const unsigned short* __restrict__ z1,
                                                    const unsigned* __restrict__ w2p,
                                                    const float* __restrict__ bias,
                                                    float* __restrict__ out) {
    __shared__ unsigned short xs[2][32 * 15 * 16];  // f16, 30720 B
    int tid = threadIdx.x;
    int n0 = blockIdx.x * 2;
#pragma unroll
    for (int img = 0; img < 2; ++img) {
        const unsigned* src = (const unsigned*)(z1 + (size_t)(n0 + img) * 7680);
        unsigned* dst = (unsigned*)xs[img];
        for (int i = tid; i < 3840; i += 768) dst[i] = src[i];
    }
    __syncthreads();
    int lane = tid & 63, wave = tid >> 6;  // wave 0..11
    int img = wave / 6;
    int oy = wave - img * 6;
    int n = n0 + img;
    float bv = bias[lane];
    float* op = out + (size_t)n * 2304 + lane * 36;
    float acc[6];
#pragma unroll
    for (int u = 0; u < 6; ++u) acc[u] = bv;
    for (int ic = 0; ic < 32; ++ic) {
#pragma unroll
        for (int ky = 0; ky < 4; ++ky) {
            const unsigned short* row = &xs[img][(ic * 15 + oy * 2 + ky) * 16];
            uint4 pa = *(const uint4*)row;        // pairs 0..3  (cols 0..7)
            uint4 pb = *(const uint4*)(row + 8);  // pairs 4..7  (cols 8..15)
            unsigned p[8] = {pa.x, pa.y, pa.z, pa.w, pb.x, pb.y, pb.z, pb.w};
            const unsigned* wpp = w2p + ((ic * 4 + ky) * 2) * 64 + lane;
            unsigned wa = wpp[0];   // kx 0,1
            unsigned wb = wpp[64];  // kx 2,3
#pragma unroll
            for (int u = 0; u < 6; ++u) {
                acc[u] = dot2(p[u], wa, acc[u]);
                acc[u] = dot2(p[u + 1], wb, acc[u]);
            }
        }
    }
#pragma unroll
    for (int u = 0; u < 6; ++u) op[oy * 6 + u] = fmaxf(acc[u], 0.0f);
}

// ---- conv3: z2 (n,64,6,6) -> relu -> (n,64,4,4)  (fp32, unchanged) ---------
__global__ __launch_bounds__(512) void conv3_kernel(const float* __restrict__ x,
                                                    const float* __restrict__ wt,
                                                    const float* __restrict__ bias,
                                                    float* __restrict__ out) {
    __shared__ float xs[4][64 * 6 * 8];  // 49152 B
    int tid = threadIdx.x;
    int n0 = blockIdx.x * 4;
    for (int img = 0; img < 4; ++img) {
        const float* src = x + (size_t)(n0 + img) * 2304;
        for (int s = tid; s < 2304; s += 512) {
            int ic = s / 36;
            int rem = s - ic * 36;
            int r = rem / 6;
            int c = rem - r * 6;
            xs[img][(ic * 6 + r) * 8 + c] = src[s];
        }
    }
    __syncthreads();
    int lane = tid & 63, wave = tid >> 6;  // 0..7
    int img = wave >> 1;
    int half = wave & 1;
    int n = n0 + img;
    float bv = bias[lane];
    float* op = out + (size_t)n * 1024 + lane * 16;
    for (int q = 0; q < 2; ++q) {
        int oy = half * 2 + q;
        float acc[4];
#pragma unroll
        for (int u = 0; u < 4; ++u) acc[u] = bv;
        for (int ic = 0; ic < 64; ++ic) {
#pragma unroll
            for (int ky = 0; ky < 3; ++ky) {
                const float* xrow = &xs[img][(ic * 6 + oy + ky) * 8];
                float xr[8];
                *(float4*)&xr[0] = *(const float4*)&xrow[0];
                *(float4*)&xr[4] = *(const float4*)&xrow[4];
                const float* wp = wt + ((ic * 3 + ky) * 3) * 64 + lane;
#pragma unroll
                for (int kx = 0; kx < 3; ++kx) {
                    float wv = wp[kx * 64];
#pragma unroll
                    for (int u = 0; u < 4; ++u) acc[u] += xr[u + kx] * wv;
                }
            }
        }
#pragma unroll
        for (int u = 0; u < 4; ++u) op[oy * 4 + u] = fmaxf(acc[u], 0.0f);
    }
}

// ---- GEMM: C(M,N) = [relu]( A(M,K) @ B(N,K)^T + bias [+ bias2] ) -----------
__global__ __launch_bounds__(256) void gemm_bt(const float* __restrict__ A,
                                               const float* __restrict__ B,
                                               const float* __restrict__ bias,
                                               const float* __restrict__ bias2,
                                               float* __restrict__ C,
                                               int M, int N, int K, int relu) {
    __shared__ float As[16][68];
    __shared__ float Bs[16][68];
    int tid = threadIdx.x;
    int m0 = blockIdx.y * 64, n0 = blockIdx.x * 64;
    int tx = tid & 15, ty = tid >> 4;
    int lr = tid >> 2;
    int lk = (tid & 3) * 4;
    const float* Ap = A + (size_t)(m0 + lr) * K + lk;
    const float* Bp = B + (size_t)(n0 + lr) * K + lk;
    float acc[4][4];
#pragma unroll
    for (int i = 0; i < 4; ++i)
#pragma unroll
        for (int j = 0; j < 4; ++j) acc[i][j] = 0.0f;

    for (int k0 = 0; k0 < K; k0 += 16) {
        float4 av = *(const float4*)(Ap + k0);
        float4 bv = *(const float4*)(Bp + k0);
        __syncthreads();
        As[lk + 0][lr] = av.x;
        As[lk + 1][lr] = av.y;
        As[lk + 2][lr] = av.z;
        As[lk + 3][lr] = av.w;
        Bs[lk + 0][lr] = bv.x;
        Bs[lk + 1][lr] = bv.y;
        Bs[lk + 2][lr] = bv.z;
        Bs[lk + 3][lr] = bv.w;
        __syncthreads();
#pragma unroll
        for (int kk = 0; kk < 16; ++kk) {
            float a[4], b[4];
            *(float4*)a = *(const float4*)&As[kk][ty * 4];
            *(float4*)b = *(const float4*)&Bs[kk][tx * 4];
#pragma unroll
            for (int i = 0; i < 4; ++i)
#pragma unroll
                for (int j = 0; j < 4; ++j) acc[i][j] += a[i] * b[j];
        }
    }
    float bb[4];
#pragma unroll
    for (int j = 0; j < 4; ++j) {
        float v = bias[n0 + tx * 4 + j];
        if (bias2) v += bias2[n0 + tx * 4 + j];
        bb[j] = v;
    }
#pragma unroll
    for (int i = 0; i < 4; ++i) {
        float4 o;
        o.x = acc[i][0] + bb[0];
        o.y = acc[i][1] + bb[1];
        o.z = acc[i][2] + bb[2];
        o.w = acc[i][3] + bb[3];
        if (relu) {
            o.x = fmaxf(o.x, 0.0f);
            o.y = fmaxf(o.y, 0.0f);
            o.z = fmaxf(o.z, 0.0f);
            o.w = fmaxf(o.w, 0.0f);
        }
        *(float4*)&C[(size_t)(m0 + ty * 4 + i) * N + n0 + tx * 4] = o;
    }
}

// ---- LSTM R12: 32 blocks (one per env), 512 threads, weights CU-resident ---
// amdgpu_waves_per_eu(2,2): 2 waves/SIMD (the minimum a 512-thread block
// needs) -> 256-VGPR budget. R11's launch_bounds(512,2) was taken as
// 2 blocks/CU -> 128-VGPR cap -> per-step scratch spill.
// Thread (u = tt&255, half = tt>>8):
//   regs:  full row half*256+u (i-gate if half=0, f-gate if half=1), 32 uint4
//          g-row 512+u, k-half = half (16 uint4)            -> 192 dw total
//   LDS:   o-row u, k-half = 1-half (read per step from wo, 128 KB)
// Per d4 of the matvec exactly one of {G-regs, O-LDS} is active (wave-uniform
// branch). half=1 posts (g_f, m*sG_hi, o_partial) via 3 KB LDS exchange;
// half=0 combines, does the thread-local c/h update, writes out + h2u.
__global__ __launch_bounds__(512)
__attribute__((amdgpu_waves_per_eu(2, 2)))
void lstm_kernel(const float* __restrict__ gi,
                 const unsigned* __restrict__ wp,
                 const int* __restrict__ done,
                 const float* __restrict__ h0,
                 const float* __restrict__ c0,
                 float* __restrict__ out) {
    __shared__ alignas(16) unsigned wo[32768];  // o-rows f16x2: [d4][256][4], 128 KB
    __shared__ alignas(16) unsigned h2u[128];   // h as f16x2, 512 B
    __shared__ float xch[768];                  // (g_f, m*sG_hi, o_part) per unit, 3 KB
    int b = blockIdx.x, tt = threadIdx.x;
    int u = tt & 255, half = tt >> 8;

    // stage o-rows (768..1023) into LDS: wo4[d4*256 + r] = wp4[d4*1024 + 768 + r]
    {
        const uint4* src = (const uint4*)wp;
        uint4* dst = (uint4*)wo;
        for (int i4 = tt; i4 < 8192; i4 += 512) {
            int d4 = i4 >> 8;
            int r = i4 & 255;
            dst[i4] = src[d4 * 1024 + 768 + r];
        }
    }

    // load register weights (coalesced: lane = row within segment)
    uint4 wrA4[32];  // row half*256 + u  (i or f gate)
    uint4 wrG4[16];  // row 512 + u, d4 = 16*half + j
    {
        const uint4* src = (const uint4*)wp;
#pragma unroll
        for (int d4 = 0; d4 < 32; ++d4) wrA4[d4] = src[d4 * 1024 + half * 256 + u];
#pragma unroll
        for (int j = 0; j < 16; ++j) wrG4[j] = src[(16 * half + j) * 1024 + 512 + u];
    }

    // init h (packed f16x2) and c
    if (tt < 128) {
        h2u[tt] = pack2_rne(h0[b * 256 + 2 * tt], h0[b * 256 + 2 * tt + 1]);
    }
    float c = 0.0f;
    if (!half) c = c0[b * 256 + u];

    const float* gbase = gi + (size_t)b * 1024;  // step stride 32*1024 floats
    float gvA = gbase[tt];        // half=0: i-gate input; half=1: f-gate input
    float gvB = gbase[512 + tt];  // half=0: g-gate input; half=1: o-gate input
    int dn = done[b];
    __syncthreads();

    const uint4* h2u4 = (const uint4*)h2u;
    const uint4* wo4 = (const uint4*)wo;

    for (int step = 0; step < 64; ++step) {
        // prefetch next step's gate inputs + done (wave-uniform branch)
        float nxA = 0.f, nxB = 0.f;
        int dnn = 0;
        if (step < 63) {
            const float* gb = gbase + (size_t)(step + 1) * 32768;
            nxA = gb[tt];
            nxB = gb[512 + tt];
            dnn = done[(step + 1) * 32 + b];
        }

        float m = 1.0f - (float)dn;
        float sA = 0.f, sG = 0.f, sO = 0.f;
#pragma unroll
        for (int d4 = 0; d4 < 32; ++d4) {
            uint4 ha = h2u4[d4];  // broadcast (uniform address)
            uint4 wa = wrA4[d4];
            sA = dot2(ha.x, wa.x, sA);
            sA = dot2(ha.y, wa.y, sA);
            sA = dot2(ha.z, wa.z, sA);
            sA = dot2(ha.w, wa.w, sA);
            if ((d4 >> 4) == half) {  // G half (registers)
                uint4 wg = wrG4[d4 & 15];
                sG = dot2(ha.x, wg.x, sG);
                sG = dot2(ha.y, wg.y, sG);
                sG = dot2(ha.z, wg.z, sG);
                sG = dot2(ha.w, wg.w, sG);
            } else {                  // O half (LDS, conflict-free b128)
                uint4 wv = wo4[d4 * 256 + u];
                sO = dot2(ha.x, wv.x, sO);
                sO = dot2(ha.y, wv.y, sO);
                sO = dot2(ha.z, wv.z, sO);
                sO = dot2(ha.w, wv.w, sO);
            }
        }

        if (half) {
            // f-gate full, g-gate hi half, o-gate lo half (+ its gi input)
            xch[u] = gvA + m * sA;
            xch[256 + u] = m * sG;
            xch[512 + u] = gvB + m * sO;
        }
        __syncthreads();  // exchange visible; all matvec h2u reads done
        if (!half) {
            float g_i = gvA + m * sA;
            float g_f = xch[u];
            float g_g = gvB + m * sG + xch[256 + u];
            float g_o = m * sO + xch[512 + u];
            float si = 1.0f / (1.0f + __expf(-g_i));
            float sf = 1.0f / (1.0f + __expf(-g_f));
            float so = 1.0f / (1.0f + __expf(-g_o));
            float tg = fast_tanh(g_g);
            c = sf * (c * m) + si * tg;
            float hn = so * fast_tanh(c);
            out[((size_t)step * 32 + b) * 256 + u] = hn;
            float hn2 = __shfl_xor(hn, 1);
            if ((u & 1) == 0) {
                unsigned lo = f2h_bits(hn);
                unsigned hi = f2h_bits(hn2);
                h2u[u >> 1] = lo | (hi << 16);
            }
        }
        __syncthreads();  // new h visible before next step's reads

        gvA = nxA; gvB = nxB;
        dn = dnn;
    }
}

// ---------------------------------------------------------------------------
extern "C" void kernel_launch(void* const* d_in, const int* in_sizes, int n_in,
                              void* d_out, int out_size, void* d_ws, size_t ws_size,
                              hipStream_t stream) {
    const float* x    = (const float*)d_in[0];
    const int*   done = (const int*)d_in[1];
    const float* w1   = (const float*)d_in[2];
    const float* b1   = (const float*)d_in[3];
    const float* w2   = (const float*)d_in[4];
    const float* b2   = (const float*)d_in[5];
    const float* w3   = (const float*)d_in[6];
    const float* b3   = (const float*)d_in[7];
    const float* fcw  = (const float*)d_in[8];
    const float* fcb  = (const float*)d_in[9];
    const float* wih  = (const float*)d_in[10];
    const float* whh  = (const float*)d_in[11];
    const float* bih  = (const float*)d_in[12];
    const float* bhh  = (const float*)d_in[13];
    const float* h0   = (const float*)d_in[14];
    const float* c0   = (const float*)d_in[15];
    float* out = (float*)d_out;
    float* ws = (float*)d_ws;

    // workspace layout (float offsets):
    // z1u (f16): [0, 7,864,320) FLOATS of shorts -- (2048, 32, 15, 16)
    // z2:        [8,000,000, 12,718,592)
    // z3:        [0, 2,097,152)           (z1u dead after conv2)
    // feats:     [2,097,152, 3,145,728)
    // gi:        [3,145,728, 5,242,880)
    // w3t:       [13,000,000, +36,864)
    // w1p:       [13,100,000, +4,096)   (uint)
    // w2p:       [13,200,000, +16,384)  (uint)
    // wp (whh packed f16x2, uint[131072]): [13,300,000, 13,431,072)
    //   NOTE: wp MUST live past z1u's end (7,864,320) -- conv1 writes z1u
    //   after the pack kernels run. R9 had it at 5.5M and got clobbered.
    unsigned short* z1u = (unsigned short*)(ws + 0);
    float* z2    = ws + 8000000;
    float* z3    = ws + 0;
    float* feats = ws + 2097152;
    float* gi    = ws + 3145728;
    float* w3t   = ws + 13000000;
    unsigned* w1p = (unsigned*)(ws + 13100000);
    unsigned* w2p = (unsigned*)(ws + 13200000);
    unsigned* wp  = (unsigned*)(ws + 13300000);

    transpose_kernel<<<(64 * 576 + 255) / 256, 256, 0, stream>>>(w3, w3t, 64, 576);
    pack_whh_pairs_kernel<<<512, 256, 0, stream>>>(whh, wp);
    pack_w1_kernel<<<16, 256, 0, stream>>>(w1, w1p);
    pack_w2_kernel<<<64, 256, 0, stream>>>(w2, w2p);

    conv1_kernel<<<NIMG, 1024, 0, stream>>>(x, w1p, b1, z1u);
    conv2_kernel<<<NIMG / 2, 768, 0, stream>>>(z1u, w2p, b2, z2);
    conv3_kernel<<<NIMG / 4, 512, 0, stream>>>(z2, w3t, b3, z3);

    gemm_bt<<<dim3(512 / 64, NIMG / 64), 256, 0, stream>>>(z3, fcw, fcb, nullptr, feats,
                                                           NIMG, 512, 1024, 1);
    gemm_bt<<<dim3(1024 / 64, NIMG / 64), 256, 0, stream>>>(feats, wih, bih, bhh, gi,
                                                            NIMG, 1024, 512, 0);

    lstm_kernel<<<32, 512, 0, stream>>>(gi, wp, done, h0, c0, out);
}

// Round 5
// 648.260 us; speedup vs baseline: 1.5031x; 1.5031x over previous
//
#include <hip/hip_runtime.h>
#include <math.h>

// ---------------------------------------------------------------------------
// RecurrentNatureCNN: conv1(8x8,s4) -> conv2(4x4,s2) -> conv3(3x3,s1) -> FC
//                     -> LSTM(T=64,B=32,H=256)
// N = T*B = 2048 images.
// R13: LSTM register residency redesigned to FIT the 128-VGPR budget instead
//      of fighting for a bigger one. R10-R12 evidence: compiler budgets 128
//      VGPRs regardless of launch_bounds 2nd arg / amdgpu_waves_per_eu, and
//      large local arrays never promote (spill to scratch: WRITE_SIZE 8.6MB).
//      R13: 1024 threads (budget=128 is forced by geometry), thread (u,q)
//      owns k-quarter q of rows u/256+u/512+u = 96 dw in 24 NAMED uint4
//      (no arrays, macro-unrolled). O-gate in LDS (128 KB). 16 KB LDS
//      exchange reduces partials over q; q==0 waves do the c/h update.
//      Full 512 KB whh on-CU: 384 KB regs + 128 KB LDS.
//      conv/GEMM stages unchanged from R8.
// ---------------------------------------------------------------------------

#define NIMG 2048

typedef _Float16 half2_t __attribute__((ext_vector_type(2)));
typedef __fp16 fp16x2_t __attribute__((ext_vector_type(2)));

__device__ inline unsigned short f2h_bits(float f) {
    union { _Float16 h; unsigned short u; } x;
    x.h = (_Float16)f;
    return x.u;
}

__device__ inline unsigned pack2_rne(float a, float b) {
    return (unsigned)f2h_bits(a) | ((unsigned)f2h_bits(b) << 16);
}

__device__ inline unsigned pack2_fast(float a, float b) {
#if __has_builtin(__builtin_amdgcn_cvt_pkrtz)
    union { fp16x2_t h; unsigned u; } x;
    x.h = __builtin_amdgcn_cvt_pkrtz(a, b);
    return x.u;
#else
    return pack2_rne(a, b);
#endif
}

__device__ inline float dot2(unsigned hu, unsigned wu, float acc) {
    union { unsigned u; half2_t h; } a, b;
    a.u = hu; b.u = wu;
#if __has_builtin(__builtin_amdgcn_fdot2)
    return __builtin_amdgcn_fdot2(a.h, b.h, acc, false);
#else
    return acc + (float)a.h.x * (float)b.h.x + (float)a.h.y * (float)b.h.y;
#endif
}

__device__ inline float fast_tanh(float x) {
    return 1.0f - 2.0f / (__expf(2.0f * x) + 1.0f);
}

// ---- generic small transpose: in (R,C) -> out (C,R) -----------------------
__global__ void transpose_kernel(const float* __restrict__ in, float* __restrict__ out,
                                 int R, int C) {
    int idx = blockIdx.x * 256 + threadIdx.x;
    if (idx < R * C) {
        int r = idx / C, c = idx - r * C;
        out[c * R + r] = in[idx];
    }
}

// ---- pack whh (1024,256) fp32 -> f16x2 pairs, uint4-interleaved by row -----
// As uint4: wp4[d4*1024 + row] = row's packed k = [d4*8, d4*8+8).
__global__ void pack_whh_pairs_kernel(const float* __restrict__ whh,
                                      unsigned* __restrict__ wp) {
    int idx = blockIdx.x * 256 + threadIdx.x;  // 0..131071
    if (idx >= 131072) return;
    int d4 = idx >> 12;
    int rem = idx & 4095;
    int row = rem >> 2;
    int j = idx & 3;
    int k0 = d4 * 8 + j * 2;
    const float* src = whh + (size_t)row * 256 + k0;
    wp[idx] = pack2_rne(src[0], src[1]);
}

// ---- pack w1 (32,4,8,8) fp32 -> f16x2 pairs along kx: w1p[oc][ic][ky][kxp] -
__global__ void pack_w1_kernel(const float* __restrict__ w1, unsigned* __restrict__ w1p) {
    int idx = blockIdx.x * 256 + threadIdx.x;  // 0..4095
    if (idx >= 4096) return;
    int oc = idx >> 7, rem = idx & 127;
    int ic = rem >> 5, ky = (rem >> 2) & 7, kxp = rem & 3;
    const float* src = w1 + (((size_t)oc * 4 + ic) * 8 + ky) * 8 + kxp * 2;
    w1p[idx] = pack2_rne(src[0], src[1]);
}

// ---- pack w2 (64,32,4,4) fp32 -> f16x2 pairs: w2p[(ic*4+ky)*2+kxp][oc] -----
__global__ void pack_w2_kernel(const float* __restrict__ w2, unsigned* __restrict__ w2p) {
    int idx = blockIdx.x * 256 + threadIdx.x;  // 0..16383
    if (idx >= 16384) return;
    int p = idx >> 6, oc = idx & 63;
    int ic = p >> 3, ky = (p >> 1) & 3, kxp = p & 1;
    const float* src = w2 + (size_t)oc * 512 + ic * 16 + ky * 4 + kxp * 2;
    w2p[idx] = pack2_rne(src[0], src[1]);
}

// ---- conv1: x (n,4,64,64)/255 -> relu -> z1 f16 (n,32,15,16 padded) --------
__global__ __launch_bounds__(1024) void conv1_kernel(const float* __restrict__ x,
                                                     const unsigned* __restrict__ w1p,
                                                     const float* __restrict__ b,
                                                     unsigned short* __restrict__ z1) {
    __shared__ unsigned short xs[4 * 64 * 64];  // f16, 32768 B
    int n = blockIdx.x;
    int tid = threadIdx.x;
    const float* xp = x + (size_t)n * 16384;
    const float inv = 1.0f / 255.0f;
    for (int i = tid * 4; i < 16384; i += 4096) {
        float4 v = *(const float4*)(xp + i);
        uint2 q;
        q.x = pack2_fast(v.x * inv, v.y * inv);
        q.y = pack2_fast(v.z * inv, v.w * inv);
        *(uint2*)&xs[i] = q;
    }
    __syncthreads();
    int lane = tid & 63, wave = tid >> 6;
    int gg = __builtin_amdgcn_readfirstlane(wave & 3);
    int pos = (wave >> 2) * 64 + lane;  // 0..255
    if (pos < 225) {
        int oy = pos / 15, ox = pos - oy * 15;
        float acc[8];
        const float* bp = b + gg * 8;
#pragma unroll
        for (int u = 0; u < 8; ++u) acc[u] = bp[u];
        for (int ic = 0; ic < 4; ++ic) {
#pragma unroll
            for (int ky = 0; ky < 8; ++ky) {
                const unsigned short* row = &xs[(ic * 64 + oy * 4 + ky) * 64 + ox * 4];
                uint2 qa = *(const uint2*)row;        // cols +0..3 (2 pairs)
                uint2 qb = *(const uint2*)(row + 4);  // cols +4..7 (2 pairs)
                const unsigned* wp = w1p + ((((gg * 8) * 4 + ic) * 8 + ky) * 4);
#pragma unroll
                for (int u = 0; u < 8; ++u) {
                    const unsigned* wu = wp + u * 128;  // (oc stride 4*8*4)
                    acc[u] = dot2(qa.x, wu[0], acc[u]);
                    acc[u] = dot2(qa.y, wu[1], acc[u]);
                    acc[u] = dot2(qb.x, wu[2], acc[u]);
                    acc[u] = dot2(qb.y, wu[3], acc[u]);
                }
            }
        }
        unsigned short* op = z1 + (size_t)n * 7680 + (gg * 8) * 240 + oy * 16 + ox;
#pragma unroll
        for (int u = 0; u < 8; ++u) op[u * 240] = f2h_bits(fmaxf(acc[u], 0.0f));
    }
}

// ---- conv2: z1 f16 (n,32,15,16) -> relu -> z2 fp32 (n,64,6,6) --------------
__global__ __launch_bounds__(768) void conv2_kernel(const unsigned short* __restrict__ z1,
                                                    const unsigned* __restrict__ w2p,
                                                    const float* __restrict__ bias,
                                                    float* __restrict__ out) {
    __shared__ unsigned short xs[2][32 * 15 * 16];  // f16, 30720 B
    int tid = threadIdx.x;
    int n0 = blockIdx.x * 2;
#pragma unroll
    for (int img = 0; img < 2; ++img) {
        const unsigned* src = (const unsigned*)(z1 + (size_t)(n0 + img) * 7680);
        unsigned* dst = (unsigned*)xs[img];
        for (int i = tid; i < 3840; i += 768) dst[i] = src[i];
    }
    __syncthreads();
    int lane = tid & 63, wave = tid >> 6;  // wave 0..11
    int img = wave / 6;
    int oy = wave - img * 6;
    int n = n0 + img;
    float bv = bias[lane];
    float* op = out + (size_t)n * 2304 + lane * 36;
    float acc[6];
#pragma unroll
    for (int u = 0; u < 6; ++u) acc[u] = bv;
    for (int ic = 0; ic < 32; ++ic) {
#pragma unroll
        for (int ky = 0; ky < 4; ++ky) {
            const unsigned short* row = &xs[img][(ic * 15 + oy * 2 + ky) * 16];
            uint4 pa = *(const uint4*)row;        // pairs 0..3  (cols 0..7)
            uint4 pb = *(const uint4*)(row + 8);  // pairs 4..7  (cols 8..15)
            unsigned p[8] = {pa.x, pa.y, pa.z, pa.w, pb.x, pb.y, pb.z, pb.w};
            const unsigned* wpp = w2p + ((ic * 4 + ky) * 2) * 64 + lane;
            unsigned wa = wpp[0];   // kx 0,1
            unsigned wb = wpp[64];  // kx 2,3
#pragma unroll
            for (int u = 0; u < 6; ++u) {
                acc[u] = dot2(p[u], wa, acc[u]);
                acc[u] = dot2(p[u + 1], wb, acc[u]);
            }
        }
    }
#pragma unroll
    for (int u = 0; u < 6; ++u) op[oy * 6 + u] = fmaxf(acc[u], 0.0f);
}

// ---- conv3: z2 (n,64,6,6) -> relu -> (n,64,4,4)  (fp32, unchanged) ---------
__global__ __launch_bounds__(512) void conv3_kernel(const float* __restrict__ x,
                                                    const float* __restrict__ wt,
                                                    const float* __restrict__ bias,
                                                    float* __restrict__ out) {
    __shared__ float xs[4][64 * 6 * 8];  // 49152 B
    int tid = threadIdx.x;
    int n0 = blockIdx.x * 4;
    for (int img = 0; img < 4; ++img) {
        const float* src = x + (size_t)(n0 + img) * 2304;
        for (int s = tid; s < 2304; s += 512) {
            int ic = s / 36;
            int rem = s - ic * 36;
            int r = rem / 6;
            int c = rem - r * 6;
            xs[img][(ic * 6 + r) * 8 + c] = src[s];
        }
    }
    __syncthreads();
    int lane = tid & 63, wave = tid >> 6;  // 0..7
    int img = wave >> 1;
    int half = wave & 1;
    int n = n0 + img;
    float bv = bias[lane];
    float* op = out + (size_t)n * 1024 + lane * 16;
    for (int q = 0; q < 2; ++q) {
        int oy = half * 2 + q;
        float acc[4];
#pragma unroll
        for (int u = 0; u < 4; ++u) acc[u] = bv;
        for (int ic = 0; ic < 64; ++ic) {
#pragma unroll
            for (int ky = 0; ky < 3; ++ky) {
                const float* xrow = &xs[img][(ic * 6 + oy + ky) * 8];
                float xr[8];
                *(float4*)&xr[0] = *(const float4*)&xrow[0];
                *(float4*)&xr[4] = *(const float4*)&xrow[4];
                const float* wp = wt + ((ic * 3 + ky) * 3) * 64 + lane;
#pragma unroll
                for (int kx = 0; kx < 3; ++kx) {
                    float wv = wp[kx * 64];
#pragma unroll
                    for (int u = 0; u < 4; ++u) acc[u] += xr[u + kx] * wv;
                }
            }
        }
#pragma unroll
        for (int u = 0; u < 4; ++u) op[oy * 4 + u] = fmaxf(acc[u], 0.0f);
    }
}

// ---- GEMM: C(M,N) = [relu]( A(M,K) @ B(N,K)^T + bias [+ bias2] ) -----------
__global__ __launch_bounds__(256) void gemm_bt(const float* __restrict__ A,
                                               const float* __restrict__ B,
                                               const float* __restrict__ bias,
                                               const float* __restrict__ bias2,
                                               float* __restrict__ C,
                                               int M, int N, int K, int relu) {
    __shared__ float As[16][68];
    __shared__ float Bs[16][68];
    int tid = threadIdx.x;
    int m0 = blockIdx.y * 64, n0 = blockIdx.x * 64;
    int tx = tid & 15, ty = tid >> 4;
    int lr = tid >> 2;
    int lk = (tid & 3) * 4;
    const float* Ap = A + (size_t)(m0 + lr) * K + lk;
    const float* Bp = B + (size_t)(n0 + lr) * K + lk;
    float acc[4][4];
#pragma unroll
    for (int i = 0; i < 4; ++i)
#pragma unroll
        for (int j = 0; j < 4; ++j) acc[i][j] = 0.0f;

    for (int k0 = 0; k0 < K; k0 += 16) {
        float4 av = *(const float4*)(Ap + k0);
        float4 bv = *(const float4*)(Bp + k0);
        __syncthreads();
        As[lk + 0][lr] = av.x;
        As[lk + 1][lr] = av.y;
        As[lk + 2][lr] = av.z;
        As[lk + 3][lr] = av.w;
        Bs[lk + 0][lr] = bv.x;
        Bs[lk + 1][lr] = bv.y;
        Bs[lk + 2][lr] = bv.z;
        Bs[lk + 3][lr] = bv.w;
        __syncthreads();
#pragma unroll
        for (int kk = 0; kk < 16; ++kk) {
            float a[4], b[4];
            *(float4*)a = *(const float4*)&As[kk][ty * 4];
            *(float4*)b = *(const float4*)&Bs[kk][tx * 4];
#pragma unroll
            for (int i = 0; i < 4; ++i)
#pragma unroll
                for (int j = 0; j < 4; ++j) acc[i][j] += a[i] * b[j];
        }
    }
    float bb[4];
#pragma unroll
    for (int j = 0; j < 4; ++j) {
        float v = bias[n0 + tx * 4 + j];
        if (bias2) v += bias2[n0 + tx * 4 + j];
        bb[j] = v;
    }
#pragma unroll
    for (int i = 0; i < 4; ++i) {
        float4 o;
        o.x = acc[i][0] + bb[0];
        o.y = acc[i][1] + bb[1];
        o.z = acc[i][2] + bb[2];
        o.w = acc[i][3] + bb[3];
        if (relu) {
            o.x = fmaxf(o.x, 0.0f);
            o.y = fmaxf(o.y, 0.0f);
            o.z = fmaxf(o.z, 0.0f);
            o.w = fmaxf(o.w, 0.0f);
        }
        *(float4*)&C[(size_t)(m0 + ty * 4 + i) * N + n0 + tx * 4] = o;
    }
}

// ---- LSTM R13: 32 blocks (one per env), 1024 threads --------------------
// Thread (u = tt&255, q = tt>>8) owns k-quarter q (64 of 256 h-values) of
// gate rows u (i), 256+u (f), 512+u (g): 24 NAMED uint4 = 96 dw in regs
// (fits the 128-VGPR budget that a 1024-thread block forces). O-gate row u
// lives in LDS (128 KB); thread reads its k-quarter (8x ds_read_b128,
// conflict-free). Partials reduced over q via 16 KB LDS exchange; q==0
// waves (wave-uniform) do the thread-local c/h update + h broadcast.
// Full 512 KB whh on-CU: 384 KB regs + 128 KB LDS. No attributes needed.
__global__ __launch_bounds__(1024) void lstm_kernel(const float* __restrict__ gi,
                                                    const unsigned* __restrict__ wp,
                                                    const int* __restrict__ done,
                                                    const float* __restrict__ h0,
                                                    const float* __restrict__ c0,
                                                    float* __restrict__ out) {
    __shared__ alignas(16) unsigned wo[32768];  // o-rows f16x2: [d4][256][4], 128 KB
    __shared__ alignas(16) unsigned h2u[128];   // h as f16x2, 512 B
    __shared__ float xch[4096];                 // partials [q][gate][u], 16 KB
    int b = blockIdx.x, tt = threadIdx.x;
    int u = tt & 255, q = tt >> 8;
    int q8 = q * 8;

    const uint4* wsrc = (const uint4*)wp;

    // stage o-rows (768..1023) into LDS: wo4[d4*256 + r] = wp4[d4*1024 + 768 + r]
    {
        uint4* dst = (uint4*)wo;
        for (int i4 = tt; i4 < 8192; i4 += 1024) {
            int d4 = i4 >> 8, r = i4 & 255;
            dst[i4] = wsrc[d4 * 1024 + 768 + r];
        }
    }

    // 24 named register weights: k-octets q8..q8+7 of rows u / 256+u / 512+u
#define LDW(j)                                              \
    uint4 wi##j = wsrc[(q8 + j) * 1024 + u];                \
    uint4 wf##j = wsrc[(q8 + j) * 1024 + 256 + u];          \
    uint4 wg##j = wsrc[(q8 + j) * 1024 + 512 + u];
    LDW(0) LDW(1) LDW(2) LDW(3) LDW(4) LDW(5) LDW(6) LDW(7)
#undef LDW

    // init h (packed f16x2) and per-unit state (q==0 threads only)
    if (tt < 128) {
        h2u[tt] = pack2_rne(h0[b * 256 + 2 * tt], h0[b * 256 + 2 * tt + 1]);
    }
    float c = 0.0f;
    float gv0 = 0.f, gv1 = 0.f, gv2 = 0.f, gv3 = 0.f;
    int dn = 0;
    const float* gbase = gi + (size_t)b * 1024;  // step stride 32*1024 floats
    if (q == 0) {
        c = c0[b * 256 + u];
        gv0 = gbase[u];
        gv1 = gbase[256 + u];
        gv2 = gbase[512 + u];
        gv3 = gbase[768 + u];
        dn = done[b];
    }
    __syncthreads();

    const uint4* h2u4 = (const uint4*)h2u;
    const uint4* wo4 = (const uint4*)wo;

    for (int step = 0; step < 64; ++step) {
        // prefetch next step's gate inputs + done (q==0 waves, wave-uniform)
        float nx0 = 0.f, nx1 = 0.f, nx2 = 0.f, nx3 = 0.f;
        int dnn = 0;
        if (q == 0 && step < 63) {
            const float* gb = gbase + (size_t)(step + 1) * 32768;
            nx0 = gb[u];
            nx1 = gb[256 + u];
            nx2 = gb[512 + u];
            nx3 = gb[768 + u];
            dnn = done[(step + 1) * 32 + b];
        }

        float pI = 0.f, pF = 0.f, pG = 0.f, pO = 0.f;
#define MV(j) {                                                         \
        uint4 ha = h2u4[q8 + j];      /* broadcast (uniform addr) */    \
        uint4 wv = wo4[(q8 + j) * 256 + u]; /* o row, conflict-free */  \
        pI = dot2(ha.x, wi##j.x, pI); pI = dot2(ha.y, wi##j.y, pI);     \
        pI = dot2(ha.z, wi##j.z, pI); pI = dot2(ha.w, wi##j.w, pI);     \
        pF = dot2(ha.x, wf##j.x, pF); pF = dot2(ha.y, wf##j.y, pF);     \
        pF = dot2(ha.z, wf##j.z, pF); pF = dot2(ha.w, wf##j.w, pF);     \
        pG = dot2(ha.x, wg##j.x, pG); pG = dot2(ha.y, wg##j.y, pG);     \
        pG = dot2(ha.z, wg##j.z, pG); pG = dot2(ha.w, wg##j.w, pG);     \
        pO = dot2(ha.x, wv.x, pO);    pO = dot2(ha.y, wv.y, pO);        \
        pO = dot2(ha.z, wv.z, pO);    pO = dot2(ha.w, wv.w, pO); }
        MV(0) MV(1) MV(2) MV(3) MV(4) MV(5) MV(6) MV(7)
#undef MV

        // post partials: xch[q*1024 + gate*256 + u]
        xch[q * 1024 + u] = pI;
        xch[q * 1024 + 256 + u] = pF;
        xch[q * 1024 + 512 + u] = pG;
        xch[q * 1024 + 768 + u] = pO;
        __syncthreads();  // partials visible; all h2u reads of this step done

        if (q == 0) {
            float sI = xch[u] + xch[1024 + u] + xch[2048 + u] + xch[3072 + u];
            float sF = xch[256 + u] + xch[1280 + u] + xch[2304 + u] + xch[3328 + u];
            float sG = xch[512 + u] + xch[1536 + u] + xch[2560 + u] + xch[3584 + u];
            float sO = xch[768 + u] + xch[1792 + u] + xch[2816 + u] + xch[3840 + u];
            float m = 1.0f - (float)dn;
            float g_i = gv0 + m * sI;
            float g_f = gv1 + m * sF;
            float g_g = gv2 + m * sG;
            float g_o = gv3 + m * sO;
            float si = 1.0f / (1.0f + __expf(-g_i));
            float sf = 1.0f / (1.0f + __expf(-g_f));
            float so = 1.0f / (1.0f + __expf(-g_o));
            float tg = fast_tanh(g_g);
            c = sf * (c * m) + si * tg;
            float hn = so * fast_tanh(c);
            out[((size_t)step * 32 + b) * 256 + u] = hn;
            float hn2 = __shfl_xor(hn, 1);
            if ((u & 1) == 0) {
                unsigned lo = f2h_bits(hn);
                unsigned hi = f2h_bits(hn2);
                h2u[u >> 1] = lo | (hi << 16);
            }
        }
        __syncthreads();  // new h + freed xch visible before next step

        gv0 = nx0; gv1 = nx1; gv2 = nx2; gv3 = nx3;
        dn = dnn;
    }
}

// ---------------------------------------------------------------------------
extern "C" void kernel_launch(void* const* d_in, const int* in_sizes, int n_in,
                              void* d_out, int out_size, void* d_ws, size_t ws_size,
                              hipStream_t stream) {
    const float* x    = (const float*)d_in[0];
    const int*   done = (const int*)d_in[1];
    const float* w1   = (const float*)d_in[2];
    const float* b1   = (const float*)d_in[3];
    const float* w2   = (const float*)d_in[4];
    const float* b2   = (const float*)d_in[5];
    const float* w3   = (const float*)d_in[6];
    const float* b3   = (const float*)d_in[7];
    const float* fcw  = (const float*)d_in[8];
    const float* fcb  = (const float*)d_in[9];
    const float* wih  = (const float*)d_in[10];
    const float* whh  = (const float*)d_in[11];
    const float* bih  = (const float*)d_in[12];
    const float* bhh  = (const float*)d_in[13];
    const float* h0   = (const float*)d_in[14];
    const float* c0   = (const float*)d_in[15];
    float* out = (float*)d_out;
    float* ws = (float*)d_ws;

    // workspace layout (float offsets):
    // z1u (f16): [0, 7,864,320) FLOATS of shorts -- (2048, 32, 15, 16)
    // z2:        [8,000,000, 12,718,592)
    // z3:        [0, 2,097,152)           (z1u dead after conv2)
    // feats:     [2,097,152, 3,145,728)
    // gi:        [3,145,728, 5,242,880)
    // w3t:       [13,000,000, +36,864)
    // w1p:       [13,100,000, +4,096)   (uint)
    // w2p:       [13,200,000, +16,384)  (uint)
    // wp (whh packed f16x2, uint[131072]): [13,300,000, 13,431,072)
    //   NOTE: wp MUST live past z1u's end (7,864,320) -- conv1 writes z1u
    //   after the pack kernels run. R9 had it at 5.5M and got clobbered.
    unsigned short* z1u = (unsigned short*)(ws + 0);
    float* z2    = ws + 8000000;
    float* z3    = ws + 0;
    float* feats = ws + 2097152;
    float* gi    = ws + 3145728;
    float* w3t   = ws + 13000000;
    unsigned* w1p = (unsigned*)(ws + 13100000);
    unsigned* w2p = (unsigned*)(ws + 13200000);
    unsigned* wp  = (unsigned*)(ws + 13300000);

    transpose_kernel<<<(64 * 576 + 255) / 256, 256, 0, stream>>>(w3, w3t, 64, 576);
    pack_whh_pairs_kernel<<<512, 256, 0, stream>>>(whh, wp);
    pack_w1_kernel<<<16, 256, 0, stream>>>(w1, w1p);
    pack_w2_kernel<<<64, 256, 0, stream>>>(w2, w2p);

    conv1_kernel<<<NIMG, 1024, 0, stream>>>(x, w1p, b1, z1u);
    conv2_kernel<<<NIMG / 2, 768, 0, stream>>>(z1u, w2p, b2, z2);
    conv3_kernel<<<NIMG / 4, 512, 0, stream>>>(z2, w3t, b3, z3);

    gemm_bt<<<dim3(512 / 64, NIMG / 64), 256, 0, stream>>>(z3, fcw, fcb, nullptr, feats,
                                                           NIMG, 512, 1024, 1);
    gemm_bt<<<dim3(1024 / 64, NIMG / 64), 256, 0, stream>>>(feats, wih, bih, bhh, gi,
                                                            NIMG, 1024, 512, 0);

    lstm_kernel<<<32, 1024, 0, stream>>>(gi, wp, done, h0, c0, out);
}